// Round 4
// baseline (4720.015 us; speedup 1.0000x reference)
//
#include <hip/hip_runtime.h>

#define EMB 64
#define BROWS 128
#define BSHIFT 7
#define LDSN 2048          // max buckets supported (2048*128 = 262144 rows)
#define CHUNK 16384        // edges per scatter block

// ---- bucket histogram (LDS-privatized) ----
__global__ __launch_bounds__(256) void bucket_hist(const int* __restrict__ rows,
                                                   int* __restrict__ counts,
                                                   int nnz, int nbuck) {
    __shared__ int lc[LDSN];
    for (int i = threadIdx.x; i < LDSN; i += 256) lc[i] = 0;
    __syncthreads();
    int stride = gridDim.x * blockDim.x;
    for (int i = blockIdx.x * blockDim.x + threadIdx.x; i < nnz; i += stride)
        atomicAdd(&lc[rows[i] >> BSHIFT], 1);
    __syncthreads();
    for (int i = threadIdx.x; i < nbuck; i += 256) {
        int v = lc[i];
        if (v) atomicAdd(&counts[i], v);
    }
}

// ---- exclusive scan of bucket counts (single block) ----
__global__ void scan_buckets(const int* __restrict__ counts, int* __restrict__ bstart,
                             int* __restrict__ cursor, int nbuck) {
    __shared__ int lds[256];
    int tid = threadIdx.x;
    int run = 0;
    for (int base = 0; base < nbuck; base += 256) {
        int idx = base + tid;
        int v = (idx < nbuck) ? counts[idx] : 0;
        int x = v;
        lds[tid] = x; __syncthreads();
        for (int off = 1; off < 256; off <<= 1) {
            int t = (tid >= off) ? lds[tid - off] : 0;
            __syncthreads();
            x += t; lds[tid] = x; __syncthreads();
        }
        if (idx < nbuck) { int ex = run + x - v; bstart[idx] = ex; cursor[idx] = ex; }
        int tot = lds[255];
        __syncthreads();
        run += tot;
    }
    if (tid == 0) bstart[nbuck] = run;
}

// ---- bucket scatter: per-block run reservation (1 atomic per bucket per block) ----
// packed word0 = col | (row_local << 18)   (col < 2^18, row_local < 128)
__global__ __launch_bounds__(256) void bucket_scatter(
        const int* __restrict__ rows, const int* __restrict__ cols,
        const float* __restrict__ vals, int* __restrict__ cursor,
        int2* __restrict__ packed, int nnz) {
    __shared__ int lc[LDSN];
    __shared__ int lbase[LDSN];
    int base = blockIdx.x * CHUNK;
    int end = min(base + CHUNK, nnz);
    for (int i = threadIdx.x; i < LDSN; i += 256) lc[i] = 0;
    __syncthreads();
    for (int i = base + threadIdx.x; i < end; i += 256)
        atomicAdd(&lc[rows[i] >> BSHIFT], 1);
    __syncthreads();
    for (int i = threadIdx.x; i < LDSN; i += 256) {
        int v = lc[i];
        lbase[i] = v ? atomicAdd(&cursor[i], v) : 0;
        lc[i] = 0;   // reuse as local fill cursor
    }
    __syncthreads();
    for (int i = base + threadIdx.x; i < end; i += 256) {
        int r = rows[i];
        int bk = r >> BSHIFT;
        int slot = lbase[bk] + atomicAdd(&lc[bk], 1);
        packed[slot] = make_int2(cols[i] | ((r & (BROWS - 1)) << 18),
                                 __float_as_int(vals[i]));
    }
}

// ---- SpMM over row buckets: LDS f32 atomic accumulate, no global atomics ----
// mode 0: out = acc;  y = acc   (layer 0, x split user/item)
// mode 1: out += acc; y = acc   (layer 1)
// mode 2: out = (out+acc)/3     (layer 2)
__global__ __launch_bounds__(256) void spmm_bucket(
        const int* __restrict__ bstart, const int2* __restrict__ packed,
        const float* __restrict__ x0, const float* __restrict__ x1, int n_split,
        float* __restrict__ y, float* __restrict__ out, int n_rows, int mode) {
    __shared__ float acc[BROWS * EMB];   // 32 KB
    int b = blockIdx.x;
    int row0 = b << BSHIFT;
    int nrow = min(BROWS, n_rows - row0);
    for (int i = threadIdx.x; i < BROWS * EMB; i += 256) acc[i] = 0.f;
    __syncthreads();

    int s = bstart[b], e = bstart[b + 1];
    int w = threadIdx.x >> 6, lane = threadIdx.x & 63;
    for (int k0 = s + w * 8; k0 < e; k0 += 32) {
        int cnt = min(8, e - k0);
        int2 d[8];
        #pragma unroll
        for (int j = 0; j < 8; ++j) if (j < cnt) d[j] = packed[k0 + j];
        float xv[8];
        #pragma unroll
        for (int j = 0; j < 8; ++j) if (j < cnt) {
            int c = d[j].x & 0x3FFFF;
            const float* xp = (c < n_split) ? (x0 + ((size_t)c << 6))
                                            : (x1 + ((size_t)(c - n_split) << 6));
            xv[j] = xp[lane];
        }
        #pragma unroll
        for (int j = 0; j < 8; ++j) if (j < cnt) {
            int rl = (d[j].x >> 18) & (BROWS - 1);
            atomicAdd(&acc[(rl << 6) + lane], __int_as_float(d[j].y) * xv[j]);
        }
    }
    __syncthreads();

    int n4 = (nrow * EMB) >> 2;
    const float4* a4 = (const float4*)acc;
    float4* o4 = (float4*)(out + ((size_t)row0 << 6));
    float4* y4 = (float4*)(y + ((size_t)row0 << 6));
    for (int i = threadIdx.x; i < n4; i += 256) {
        float4 a = a4[i];
        if (mode == 0) {
            o4[i] = a; y4[i] = a;
        } else if (mode == 1) {
            float4 o = o4[i];
            o.x += a.x; o.y += a.y; o.z += a.z; o.w += a.w;
            o4[i] = o; y4[i] = a;
        } else {
            float4 o = o4[i];
            o.x = (o.x + a.x) * (1.f / 3.f);
            o.y = (o.y + a.y) * (1.f / 3.f);
            o.z = (o.z + a.z) * (1.f / 3.f);
            o.w = (o.w + a.w) * (1.f / 3.f);
            o4[i] = o;
        }
    }
}

extern "C" void kernel_launch(void* const* d_in, const int* in_sizes, int n_in,
                              void* d_out, int out_size, void* d_ws, size_t ws_size,
                              hipStream_t stream) {
    const float* user_emb = (const float*)d_in[0];
    const float* item_emb = (const float*)d_in[1];
    const int*   adj_row  = (const int*)d_in[2];
    const int*   adj_col  = (const int*)d_in[3];
    const float* adj_val  = (const float*)d_in[4];
    float* out = (float*)d_out;

    const int n_user = in_sizes[0] / EMB;
    const int n_item = in_sizes[1] / EMB;
    const int n      = n_user + n_item;
    const int nnz    = in_sizes[2];
    const size_t node_bytes = (size_t)n * EMB * sizeof(float);
    const int nbuck  = (n + BROWS - 1) >> BSHIFT;

    char* p = (char*)d_ws;
    float* A      = (float*)p; p += node_bytes;
    float* B      = (float*)p; p += node_bytes;
    int2*  packed = (int2*)p;  p += (size_t)nnz * sizeof(int2);
    int*   bstart = (int*)p;   p += (size_t)(nbuck + 1) * sizeof(int);
    int*   cursor = (int*)p;   p += (size_t)nbuck * sizeof(int);
    int*   counts = (int*)p;   p += (size_t)nbuck * sizeof(int);

    // ---- build bucketed edge list ----
    hipMemsetAsync(counts, 0, (size_t)nbuck * sizeof(int), stream);
    bucket_hist<<<256, 256, 0, stream>>>(adj_row, counts, nnz, nbuck);
    scan_buckets<<<1, 256, 0, stream>>>(counts, bstart, cursor, nbuck);
    bucket_scatter<<<(nnz + CHUNK - 1) / CHUNK, 256, 0, stream>>>(
        adj_row, adj_col, adj_val, cursor, packed, nnz);

    // ---- 3 propagation layers, fused accumulate ----
    spmm_bucket<<<nbuck, 256, 0, stream>>>(bstart, packed,
                                           user_emb, item_emb, n_user,
                                           A, out, n, 0);
    spmm_bucket<<<nbuck, 256, 0, stream>>>(bstart, packed,
                                           A, A, n,
                                           B, out, n, 1);
    spmm_bucket<<<nbuck, 256, 0, stream>>>(bstart, packed,
                                           B, B, n,
                                           A, out, n, 2);
}

// Round 5
// 764.184 us; speedup vs baseline: 6.1765x; 6.1765x over previous
//
#include <hip/hip_runtime.h>

#define EMB 64
#define BROWS 128
#define BSHIFT 7
#define LDSN 2048          // max buckets supported (2048*128 = 262144 rows)
#define CHUNK 16384        // edges per scatter block
#define SORT_CAP 5120      // per-bucket LDS staging capacity (mean 2560, sigma ~51)

// ---- bucket histogram (LDS-privatized) ----
__global__ __launch_bounds__(256) void bucket_hist(const int* __restrict__ rows,
                                                   int* __restrict__ counts,
                                                   int nnz, int nbuck) {
    __shared__ int lc[LDSN];
    for (int i = threadIdx.x; i < LDSN; i += 256) lc[i] = 0;
    __syncthreads();
    int stride = gridDim.x * blockDim.x;
    for (int i = blockIdx.x * blockDim.x + threadIdx.x; i < nnz; i += stride)
        atomicAdd(&lc[rows[i] >> BSHIFT], 1);
    __syncthreads();
    for (int i = threadIdx.x; i < nbuck; i += 256) {
        int v = lc[i];
        if (v) atomicAdd(&counts[i], v);
    }
}

// ---- exclusive scan of bucket counts (single block) ----
__global__ void scan_buckets(const int* __restrict__ counts, int* __restrict__ bstart,
                             int* __restrict__ cursor, int nbuck) {
    __shared__ int lds[256];
    int tid = threadIdx.x;
    int run = 0;
    for (int base = 0; base < nbuck; base += 256) {
        int idx = base + tid;
        int v = (idx < nbuck) ? counts[idx] : 0;
        int x = v;
        lds[tid] = x; __syncthreads();
        for (int off = 1; off < 256; off <<= 1) {
            int t = (tid >= off) ? lds[tid - off] : 0;
            __syncthreads();
            x += t; lds[tid] = x; __syncthreads();
        }
        if (idx < nbuck) { int ex = run + x - v; bstart[idx] = ex; cursor[idx] = ex; }
        int tot = lds[255];
        __syncthreads();
        run += tot;
    }
    if (tid == 0) bstart[nbuck] = run;
}

// ---- bucket scatter: per-block run reservation (1 atomic per bucket per block) ----
// packed word0 = col | (row_local << 18)   (col < 2^18, row_local < 128)
__global__ __launch_bounds__(256) void bucket_scatter(
        const int* __restrict__ rows, const int* __restrict__ cols,
        const float* __restrict__ vals, int* __restrict__ cursor,
        int2* __restrict__ packed, int nnz) {
    __shared__ int lc[LDSN];
    __shared__ int lbase[LDSN];
    int base = blockIdx.x * CHUNK;
    int end = min(base + CHUNK, nnz);
    for (int i = threadIdx.x; i < LDSN; i += 256) lc[i] = 0;
    __syncthreads();
    for (int i = base + threadIdx.x; i < end; i += 256)
        atomicAdd(&lc[rows[i] >> BSHIFT], 1);
    __syncthreads();
    for (int i = threadIdx.x; i < LDSN; i += 256) {
        int v = lc[i];
        lbase[i] = v ? atomicAdd(&cursor[i], v) : 0;
        lc[i] = 0;   // reuse as local fill cursor
    }
    __syncthreads();
    for (int i = base + threadIdx.x; i < end; i += 256) {
        int r = rows[i];
        int bk = r >> BSHIFT;
        int slot = lbase[bk] + atomicAdd(&lc[bk], 1);
        packed[slot] = make_int2(cols[i] | ((r & (BROWS - 1)) << 18),
                                 __float_as_int(vals[i]));
    }
}

// ---- per-bucket in-place counting sort by row_local; emits exact CSR offs ----
// One block per bucket. Bucket edges staged in LDS (<= SORT_CAP, 50-sigma safe),
// scattered back into the same contiguous global window in row order, with the
// row_local tag stripped (word0 becomes pure col).
__global__ __launch_bounds__(256) void sort_bucket(
        int2* __restrict__ packed, const int* __restrict__ bstart,
        int* __restrict__ offs, int n_rows, int nbuck) {
    __shared__ int2 ebuf[SORT_CAP];     // 40 KB
    __shared__ int cnt[BROWS];
    __shared__ int coff[BROWS];
    int b = blockIdx.x;
    int s = bstart[b], e = bstart[b + 1];
    int sz = e - s;
    int tid = threadIdx.x;
    if (tid < BROWS) cnt[tid] = 0;
    __syncthreads();
    for (int i = tid; i < sz; i += 256) {
        int2 ed = packed[s + i];
        ebuf[i] = ed;
        atomicAdd(&cnt[(ed.x >> 18) & (BROWS - 1)], 1);
    }
    __syncthreads();
    // exclusive scan of 128 counters (Hillis-Steele in LDS)
    int v = (tid < BROWS) ? cnt[tid] : 0;
    if (tid < BROWS) coff[tid] = v;
    __syncthreads();
    for (int off = 1; off < BROWS; off <<= 1) {
        int add = (tid < BROWS && tid >= off) ? coff[tid - off] : 0;
        __syncthreads();
        if (tid < BROWS) coff[tid] += add;
        __syncthreads();
    }
    if (tid < BROWS) {
        int ex = coff[tid] - v;
        cnt[tid] = ex;                       // becomes the fill cursor
        int row = (b << BSHIFT) + tid;
        if (row < n_rows) offs[row] = s + ex;
    }
    if (b == nbuck - 1 && tid == 0) offs[n_rows] = e;
    __syncthreads();
    for (int i = tid; i < sz; i += 256) {
        int2 ed = ebuf[i];
        int rl = (ed.x >> 18) & (BROWS - 1);
        int pos = atomicAdd(&cnt[rl], 1);
        packed[s + pos] = make_int2(ed.x & 0x3FFFF, ed.y);   // strip tag
    }
}

// ---- SpMM: one wave (64 lanes == EMB) per row; unroll-4, no arrays ----
// mode 0: out = acc;  y = acc   (layer 0, x split user/item)
// mode 1: out += acc; y = acc   (layer 1)
// mode 2: out = (out+acc)/3     (layer 2, no y write)
__global__ __launch_bounds__(256) void spmm_row(
        const int* __restrict__ offs, const int2* __restrict__ packed,
        const float* __restrict__ x0, const float* __restrict__ x1, int n_split,
        float* __restrict__ y, float* __restrict__ out, int n_rows, int mode) {
    int wid = (blockIdx.x * blockDim.x + threadIdx.x) >> 6;
    if (wid >= n_rows) return;
    int lane = threadIdx.x & 63;
    int r = __builtin_amdgcn_readfirstlane(wid);   // wave-uniform -> scalar path
    int s = offs[r];
    int e = offs[r + 1];
    float a0 = 0.f, a1 = 0.f, a2 = 0.f, a3 = 0.f;
    int k = s;
    for (; k + 3 < e; k += 4) {
        int2 c0 = packed[k];
        int2 c1 = packed[k + 1];
        int2 c2 = packed[k + 2];
        int2 c3 = packed[k + 3];
        const float* p0 = (c0.x < n_split) ? (x0 + ((size_t)c0.x << 6))
                                           : (x1 + ((size_t)(c0.x - n_split) << 6));
        const float* p1 = (c1.x < n_split) ? (x0 + ((size_t)c1.x << 6))
                                           : (x1 + ((size_t)(c1.x - n_split) << 6));
        const float* p2 = (c2.x < n_split) ? (x0 + ((size_t)c2.x << 6))
                                           : (x1 + ((size_t)(c2.x - n_split) << 6));
        const float* p3 = (c3.x < n_split) ? (x0 + ((size_t)c3.x << 6))
                                           : (x1 + ((size_t)(c3.x - n_split) << 6));
        a0 += __int_as_float(c0.y) * p0[lane];
        a1 += __int_as_float(c1.y) * p1[lane];
        a2 += __int_as_float(c2.y) * p2[lane];
        a3 += __int_as_float(c3.y) * p3[lane];
    }
    for (; k < e; ++k) {
        int2 cv = packed[k];
        const float* xp = (cv.x < n_split) ? (x0 + ((size_t)cv.x << 6))
                                           : (x1 + ((size_t)(cv.x - n_split) << 6));
        a0 += __int_as_float(cv.y) * xp[lane];
    }
    float acc = (a0 + a1) + (a2 + a3);
    size_t oi = ((size_t)r << 6) + lane;
    if (mode == 0)      { out[oi] = acc;  y[oi] = acc; }
    else if (mode == 1) { out[oi] += acc; y[oi] = acc; }
    else                { out[oi] = (out[oi] + acc) * (1.0f / 3.0f); }
}

extern "C" void kernel_launch(void* const* d_in, const int* in_sizes, int n_in,
                              void* d_out, int out_size, void* d_ws, size_t ws_size,
                              hipStream_t stream) {
    const float* user_emb = (const float*)d_in[0];
    const float* item_emb = (const float*)d_in[1];
    const int*   adj_row  = (const int*)d_in[2];
    const int*   adj_col  = (const int*)d_in[3];
    const float* adj_val  = (const float*)d_in[4];
    float* out = (float*)d_out;

    const int n_user = in_sizes[0] / EMB;
    const int n_item = in_sizes[1] / EMB;
    const int n      = n_user + n_item;
    const int nnz    = in_sizes[2];
    const size_t node_bytes = (size_t)n * EMB * sizeof(float);
    const int nbuck  = (n + BROWS - 1) >> BSHIFT;

    char* p = (char*)d_ws;
    float* A      = (float*)p; p += node_bytes;
    float* B      = (float*)p; p += node_bytes;
    int2*  packed = (int2*)p;  p += (size_t)nnz * sizeof(int2);
    int*   offs   = (int*)p;   p += (size_t)(n + 1) * sizeof(int);
    int*   bstart = (int*)p;   p += (size_t)(nbuck + 1) * sizeof(int);
    int*   cursor = (int*)p;   p += (size_t)nbuck * sizeof(int);
    int*   counts = (int*)p;   p += (size_t)nbuck * sizeof(int);

    // ---- build bucketed edge list, then exact CSR via per-bucket sort ----
    hipMemsetAsync(counts, 0, (size_t)nbuck * sizeof(int), stream);
    bucket_hist<<<256, 256, 0, stream>>>(adj_row, counts, nnz, nbuck);
    scan_buckets<<<1, 256, 0, stream>>>(counts, bstart, cursor, nbuck);
    bucket_scatter<<<(nnz + CHUNK - 1) / CHUNK, 256, 0, stream>>>(
        adj_row, adj_col, adj_val, cursor, packed, nnz);
    sort_bucket<<<nbuck, 256, 0, stream>>>(packed, bstart, offs, n, nbuck);

    // ---- 3 propagation layers, fused accumulate ----
    const int sgrid = (n * EMB + 255) / 256;   // one wave per row
    spmm_row<<<sgrid, 256, 0, stream>>>(offs, packed,
                                        user_emb, item_emb, n_user,
                                        A, out, n, 0);
    spmm_row<<<sgrid, 256, 0, stream>>>(offs, packed,
                                        A, A, n,
                                        B, out, n, 1);
    spmm_row<<<sgrid, 256, 0, stream>>>(offs, packed,
                                        B, B, n,
                                        A, out, n, 2);
}